// Round 3
// baseline (150.218 us; speedup 1.0000x reference)
//
#include <hip/hip_runtime.h>

#define NCLS 5
#define NSAMP 4194304
#define BLOCK 256
#define GRID 2048
#define SAMP_PER_BLOCK (NSAMP / GRID)          // 2048 samples/block, 8/thread
#define CHUNK_SAMP 1024                        // samples per chunk (2 chunks/block)
#define CHUNK_F4 (CHUNK_SAMP * NCLS / 4)       // 1280 float4 = 20 KB LDS
#define NVALS (2 * NCLS)                       // 5 sums + 5 counts

// CE without max-subtraction: logits are N(0,1) (|l| < ~6), exp cannot
// overflow/underflow harmfully; absmax threshold is 0.1975, error here ~1e-5.
__device__ __forceinline__ void accum_sample(float l0, float l1, float l2, float l3, float l4,
                                             int t, float sums[NCLS], unsigned int& packed_cnt) {
    float s = __expf(l0) + __expf(l1) + __expf(l2) + __expf(l3) + __expf(l4);
    float lt = (t == 0) ? l0 : (t == 1) ? l1 : (t == 2) ? l2 : (t == 3) ? l3 : l4;
    float ce = __logf(s) - lt;
#pragma unroll
    for (int k = 0; k < NCLS; ++k) {
        sums[k] += (t == k) ? ce : 0.0f;
    }
    packed_cnt += 1u << (6 * t);   // <=8 samples/thread, 6 bits/class: no overflow
}

// Block-level reduction of 10 values; threads 0..9 get the block total.
__device__ __forceinline__ void block_reduce_10(float sums[NCLS], float cnts[NCLS],
                                                float* result10) {
#pragma unroll
    for (int k = 0; k < NCLS; ++k) {
#pragma unroll
        for (int off = 32; off > 0; off >>= 1) {
            sums[k] += __shfl_down(sums[k], off, 64);
            cnts[k] += __shfl_down(cnts[k], off, 64);
        }
    }
    __shared__ float ls[BLOCK / 64][NVALS];
    const int lane = threadIdx.x & 63;
    const int wave = threadIdx.x >> 6;
    if (lane == 0) {
#pragma unroll
        for (int k = 0; k < NCLS; ++k) {
            ls[wave][k] = sums[k];
            ls[wave][NCLS + k] = cnts[k];
        }
    }
    __syncthreads();
    if (threadIdx.x < NVALS) {
        float v = 0.f;
#pragma unroll
        for (int w = 0; w < BLOCK / 64; ++w) v += ls[w][threadIdx.x];
        *result10 = v;
    }
}

// XOR swizzle on float4 slot index: linear writes stay conflict-free, and the
// stride-5-f4 reads (lanes 8 apart alias 8-way in a linear layout: 20*8=160
// words == 0 mod 32 banks) get spread across 8 distinct bank groups.
__device__ __forceinline__ int swz(int F) { return F ^ ((F >> 3) & 7); }

// Fused single kernel. Handshake (round-1 post-mortem): no __threadfence
// (agent fence = buffer_wbl2+inv per block, ~110us), no contended atomic RMW
// (~100us). Relaxed agent-scope (sc1) stores/loads to the coherent point,
// one wave-level s_waitcnt vmcnt(0) orders partials->flag, fixed reducer
// block 0 polls per-block flags.
// Streaming (round-2 post-mortem): per-lane stride-80B float4 loads are 64
// L1 transactions/instruction (no line sharing) + L1 thrash. Stage each 20KB
// chunk via coalesced loads -> LDS (swizzled) -> per-thread reads instead.
__global__ __launch_bounds__(BLOCK) void mfe_fused(const float* __restrict__ inputs,
                                                   const int* __restrict__ targets,
                                                   float* __restrict__ partial /* [NVALS][GRID] */,
                                                   unsigned int* __restrict__ flags /* [GRID] */,
                                                   float* __restrict__ out) {
    const int t = threadIdx.x;
    const int b = blockIdx.x;
    const size_t samp0 = (size_t)b * SAMP_PER_BLOCK;   // chunk 0 sample base
    const size_t samp1 = samp0 + CHUNK_SAMP;           // chunk 1 sample base

    const float4* gin0 = (const float4*)(inputs + samp0 * NCLS);
    const float4* gin1 = (const float4*)(inputs + samp1 * NCLS);

    // ---- Issue ALL global loads up front, fully coalesced (lane stride 16B) ----
    float4 g0[5], g1[5];
#pragma unroll
    for (int j = 0; j < 5; ++j) g0[j] = gin0[t + BLOCK * j];
#pragma unroll
    for (int j = 0; j < 5; ++j) g1[j] = gin1[t + BLOCK * j];
    int4 tg0 = *(const int4*)(targets + samp0 + 4 * t);
    int4 tg1 = *(const int4*)(targets + samp1 + 4 * t);

    __shared__ float4 lds[CHUNK_F4];   // 20 KB -> 8 blocks/CU LDS-wise

    float sums[NCLS] = {0.f, 0.f, 0.f, 0.f, 0.f};
    unsigned int packed = 0;
    float4 r[5];

    // ---- Chunk 0: LDS redistribute + compute ----
#pragma unroll
    for (int j = 0; j < 5; ++j) lds[swz(t + BLOCK * j)] = g0[j];
    __syncthreads();
#pragma unroll
    for (int k = 0; k < 5; ++k) r[k] = lds[swz(5 * t + k)];
    accum_sample(r[0].x, r[0].y, r[0].z, r[0].w, r[1].x, tg0.x, sums, packed);
    accum_sample(r[1].y, r[1].z, r[1].w, r[2].x, r[2].y, tg0.y, sums, packed);
    accum_sample(r[2].z, r[2].w, r[3].x, r[3].y, r[3].z, tg0.z, sums, packed);
    accum_sample(r[3].w, r[4].x, r[4].y, r[4].z, r[4].w, tg0.w, sums, packed);
    __syncthreads();

    // ---- Chunk 1 ----
#pragma unroll
    for (int j = 0; j < 5; ++j) lds[swz(t + BLOCK * j)] = g1[j];
    __syncthreads();
#pragma unroll
    for (int k = 0; k < 5; ++k) r[k] = lds[swz(5 * t + k)];
    accum_sample(r[0].x, r[0].y, r[0].z, r[0].w, r[1].x, tg1.x, sums, packed);
    accum_sample(r[1].y, r[1].z, r[1].w, r[2].x, r[2].y, tg1.y, sums, packed);
    accum_sample(r[2].z, r[2].w, r[3].x, r[3].y, r[3].z, tg1.z, sums, packed);
    accum_sample(r[3].w, r[4].x, r[4].y, r[4].z, r[4].w, tg1.w, sums, packed);

    float cnts[NCLS];
#pragma unroll
    for (int k = 0; k < NCLS; ++k) {
        cnts[k] = (float)((packed >> (6 * k)) & 63u);
    }

    float total;
    block_reduce_10(sums, cnts, &total);

    // ---- Publish partials (sc1 relaxed stores, straight to coherent point) ----
    if (threadIdx.x < NVALS) {
        __hip_atomic_store(&partial[threadIdx.x * GRID + blockIdx.x], total,
                           __ATOMIC_RELAXED, __HIP_MEMORY_SCOPE_AGENT);
    }
    // Wave 0: wait until the sc1 stores above reached the coherent point, then
    // set this block's flag. asm "memory" clobber = compiler fence.
    asm volatile("s_waitcnt vmcnt(0)" ::: "memory");
    if (threadIdx.x == 0) {
        __hip_atomic_store(&flags[blockIdx.x], 1u,
                           __ATOMIC_RELAXED, __HIP_MEMORY_SCOPE_AGENT);
    }

    if (blockIdx.x != 0) return;

    // ---- Block 0: poll all flags (relaxed sc1 loads; control dep orders HW) ----
#pragma unroll 1
    for (int i = threadIdx.x; i < GRID; i += BLOCK) {
        while (__hip_atomic_load(&flags[i], __ATOMIC_RELAXED,
                                 __HIP_MEMORY_SCOPE_AGENT) == 0u) {
            __builtin_amdgcn_s_sleep(2);
        }
    }
    __syncthreads();                       // all flags observed by whole block
    asm volatile("" ::: "memory");         // don't hoist partial loads above polls

    // ---- Final reduce: sc1 loads of the 80KB partial array ----
    float fsums[NCLS], fcnts[NCLS];
#pragma unroll
    for (int k = 0; k < NCLS; ++k) {
        float s = 0.f, c = 0.f;
#pragma unroll
        for (int i = 0; i < GRID / BLOCK; ++i) {
            s += __hip_atomic_load(&partial[k * GRID + threadIdx.x + i * BLOCK],
                                   __ATOMIC_RELAXED, __HIP_MEMORY_SCOPE_AGENT);
            c += __hip_atomic_load(&partial[(NCLS + k) * GRID + threadIdx.x + i * BLOCK],
                                   __ATOMIC_RELAXED, __HIP_MEMORY_SCOPE_AGENT);
        }
        fsums[k] = s;
        fcnts[k] = c;
    }

    float ftot;
    block_reduce_10(fsums, fcnts, &ftot);

    __shared__ float fin[NVALS];
    if (threadIdx.x < NVALS) fin[threadIdx.x] = ftot;
    __syncthreads();
    if (threadIdx.x == 0) {
        float loss = 0.f;
#pragma unroll
        for (int k = 0; k < NCLS; ++k) {
            float cnt = fin[NCLS + k];
            if (cnt > 0.f) loss += fin[k] / cnt;
        }
        out[0] = loss;
    }
}

extern "C" void kernel_launch(void* const* d_in, const int* in_sizes, int n_in,
                              void* d_out, int out_size, void* d_ws, size_t ws_size,
                              hipStream_t stream) {
    const float* inputs = (const float*)d_in[0];
    const int* targets = (const int*)d_in[1];
    float* out = (float*)d_out;
    float* partial = (float*)d_ws;                                   // NVALS*GRID floats = 80 KB
    unsigned int* flags =
        (unsigned int*)((char*)d_ws + (size_t)NVALS * GRID * sizeof(float));  // GRID uints = 8 KB

    // Workspace is poisoned between iterations: zero the flags.
    // 8 KB async memset = cheap graph memset node, no extra kernel dispatch.
    hipMemsetAsync(flags, 0, GRID * sizeof(unsigned int), stream);
    mfe_fused<<<GRID, BLOCK, 0, stream>>>(inputs, targets, partial, flags, out);
}

// Round 4
// 142.082 us; speedup vs baseline: 1.0573x; 1.0573x over previous
//
#include <hip/hip_runtime.h>

#define NCLS 5
#define NSAMP 4194304
#define BLOCK 256
#define GRID 4096
#define SAMP_PER_BLOCK (NSAMP / GRID)             // 1024 samples/block, 4/thread
#define CHUNK_F4 (SAMP_PER_BLOCK * NCLS / 4)      // 1280 float4 = 20 KB LDS
#define NVALS (2 * NCLS)                          // 5 sums + 5 counts

// CE without max-subtraction: logits are N(0,1) (|l| < ~6), exp cannot
// overflow/underflow harmfully; absmax threshold is 0.1975, error here ~1e-5.
__device__ __forceinline__ void accum_sample(float l0, float l1, float l2, float l3, float l4,
                                             int t, float sums[NCLS], unsigned int& packed_cnt) {
    float s = __expf(l0) + __expf(l1) + __expf(l2) + __expf(l3) + __expf(l4);
    float lt = (t == 0) ? l0 : (t == 1) ? l1 : (t == 2) ? l2 : (t == 3) ? l3 : l4;
    float ce = __logf(s) - lt;
#pragma unroll
    for (int k = 0; k < NCLS; ++k) {
        sums[k] += (t == k) ? ce : 0.0f;
    }
    packed_cnt += 1u << (6 * t);   // <=4 samples/thread, 6 bits/class: no overflow
}

// Block-level reduction of 10 values; threads 0..9 get the block total.
__device__ __forceinline__ void block_reduce_10(float sums[NCLS], float cnts[NCLS],
                                                float* result10) {
#pragma unroll
    for (int k = 0; k < NCLS; ++k) {
#pragma unroll
        for (int off = 32; off > 0; off >>= 1) {
            sums[k] += __shfl_down(sums[k], off, 64);
            cnts[k] += __shfl_down(cnts[k], off, 64);
        }
    }
    __shared__ float ls[BLOCK / 64][NVALS];
    const int lane = threadIdx.x & 63;
    const int wave = threadIdx.x >> 6;
    if (lane == 0) {
#pragma unroll
        for (int k = 0; k < NCLS; ++k) {
            ls[wave][k] = sums[k];
            ls[wave][NCLS + k] = cnts[k];
        }
    }
    __syncthreads();
    if (threadIdx.x < NVALS) {
        float v = 0.f;
#pragma unroll
        for (int w = 0; w < BLOCK / 64; ++w) v += ls[w][threadIdx.x];
        *result10 = v;
    }
}

// XOR swizzle on float4 slot index (involution, permutes within 8-slot/128B
// groups). Breaks the 8-way bank conflict of stride-5-f4 reads (lanes 8 apart
// alias: 20*8=160 words == 0 mod 32 banks) while keeping global access for a
// wave inside the same contiguous 1KB -> coalescing intact.
__device__ __forceinline__ int swz(int F) { return F ^ ((F >> 3) & 7); }

// global->LDS DMA, 16B/lane. Dest = wave-uniform base + lane*16 (HW rule);
// source address is per-lane. No VGPR staging -> no spill (round-3 post-mortem:
// register-staged chunks spilled 41MB to scratch).
__device__ __forceinline__ void gload_lds16(const float4* g, float4* l) {
    __builtin_amdgcn_global_load_lds(
        (__attribute__((address_space(1))) const void*)g,
        (__attribute__((address_space(3))) void*)l, 16, 0, 0);
}

// Fused single kernel. Handshake (round-1 post-mortem): no __threadfence
// (agent fence = buffer_wbl2+inv per block, ~110us), no contended atomic RMW
// (~100us). Relaxed agent-scope (sc1) stores/loads to the coherent point,
// one wave-level s_waitcnt vmcnt(0) orders partials->flag, fixed reducer
// block 0 polls per-block flags.
// Streaming (rounds 2-3 post-mortems): strided 80B-lane loads are L1-
// transaction-bound; register-staged LDS redistribution spills. Fix: direct
// global_load_lds staging (linear LDS dest, inverse-swizzled global source,
// swizzled reads — rule #21 both-sides-or-neither).
__global__ __launch_bounds__(BLOCK) void mfe_fused(const float* __restrict__ inputs,
                                                   const int* __restrict__ targets,
                                                   float* __restrict__ partial /* [NVALS][GRID] */,
                                                   unsigned int* __restrict__ flags /* [GRID] */,
                                                   float* __restrict__ out) {
    const int T = threadIdx.x;
    const int b = blockIdx.x;
    const int w = T >> 6;                       // wave id 0..3
    const int lane = T & 63;
    const size_t samp0 = (size_t)b * SAMP_PER_BLOCK;
    const float4* gin = (const float4*)(inputs + samp0 * NCLS);

    __shared__ float4 lds[CHUNK_F4];            // 20 KB -> 7 blocks/CU

    // Targets: coalesced int4 to VGPRs (only 16B/thread live — no pressure).
    int4 tg = *(const int4*)(targets + samp0 + 4 * T);

    // Stage the 20KB chunk: each wave issues 5 x 1KB global_load_lds.
    // Phys LDS slot s receives gin[swz(s)] (swz = involution), so logical
    // slot L lives at phys swz(L).
#pragma unroll
    for (int j = 0; j < 5; ++j) {
        const int base = 320 * w + 64 * j;      // wave-uniform LDS base
        gload_lds16(gin + swz(base + lane), &lds[base]);
    }
    asm volatile("s_waitcnt vmcnt(0)" ::: "memory");   // this wave's DMAs + tg done
    __syncthreads();                                    // all waves' chunks visible

    // Each thread: 4 samples = logical f4 slots [5T, 5T+5).
    float4 r[5];
#pragma unroll
    for (int k = 0; k < 5; ++k) r[k] = lds[swz(5 * T + k)];

    float sums[NCLS] = {0.f, 0.f, 0.f, 0.f, 0.f};
    unsigned int packed = 0;
    accum_sample(r[0].x, r[0].y, r[0].z, r[0].w, r[1].x, tg.x, sums, packed);
    accum_sample(r[1].y, r[1].z, r[1].w, r[2].x, r[2].y, tg.y, sums, packed);
    accum_sample(r[2].z, r[2].w, r[3].x, r[3].y, r[3].z, tg.z, sums, packed);
    accum_sample(r[3].w, r[4].x, r[4].y, r[4].z, r[4].w, tg.w, sums, packed);

    float cnts[NCLS];
#pragma unroll
    for (int k = 0; k < NCLS; ++k) {
        cnts[k] = (float)((packed >> (6 * k)) & 63u);
    }

    float total;
    block_reduce_10(sums, cnts, &total);

    // ---- Publish partials (sc1 relaxed stores, straight to coherent point) ----
    if (threadIdx.x < NVALS) {
        __hip_atomic_store(&partial[threadIdx.x * GRID + blockIdx.x], total,
                           __ATOMIC_RELAXED, __HIP_MEMORY_SCOPE_AGENT);
    }
    // Wave 0: wait until the sc1 stores above reached the coherent point, then
    // set this block's flag. asm "memory" clobber = compiler fence.
    asm volatile("s_waitcnt vmcnt(0)" ::: "memory");
    if (threadIdx.x == 0) {
        __hip_atomic_store(&flags[blockIdx.x], 1u,
                           __ATOMIC_RELAXED, __HIP_MEMORY_SCOPE_AGENT);
    }

    if (blockIdx.x != 0) return;

    // ---- Block 0: poll all flags (relaxed sc1 loads; control dep orders HW) ----
#pragma unroll 1
    for (int i = threadIdx.x; i < GRID; i += BLOCK) {
        while (__hip_atomic_load(&flags[i], __ATOMIC_RELAXED,
                                 __HIP_MEMORY_SCOPE_AGENT) == 0u) {
            __builtin_amdgcn_s_sleep(2);
        }
    }
    __syncthreads();                       // all flags observed by whole block
    asm volatile("" ::: "memory");         // don't hoist partial loads above polls

    // ---- Final reduce: sc1 loads of the 160KB partial array ----
    float fsums[NCLS], fcnts[NCLS];
#pragma unroll
    for (int k = 0; k < NCLS; ++k) {
        float s = 0.f, c = 0.f;
#pragma unroll
        for (int i = 0; i < GRID / BLOCK; ++i) {
            s += __hip_atomic_load(&partial[k * GRID + threadIdx.x + i * BLOCK],
                                   __ATOMIC_RELAXED, __HIP_MEMORY_SCOPE_AGENT);
            c += __hip_atomic_load(&partial[(NCLS + k) * GRID + threadIdx.x + i * BLOCK],
                                   __ATOMIC_RELAXED, __HIP_MEMORY_SCOPE_AGENT);
        }
        fsums[k] = s;
        fcnts[k] = c;
    }

    float ftot;
    block_reduce_10(fsums, fcnts, &ftot);

    __shared__ float fin[NVALS];
    if (threadIdx.x < NVALS) fin[threadIdx.x] = ftot;
    __syncthreads();
    if (threadIdx.x == 0) {
        float loss = 0.f;
#pragma unroll
        for (int k = 0; k < NCLS; ++k) {
            float cnt = fin[NCLS + k];
            if (cnt > 0.f) loss += fin[k] / cnt;
        }
        out[0] = loss;
    }
}

extern "C" void kernel_launch(void* const* d_in, const int* in_sizes, int n_in,
                              void* d_out, int out_size, void* d_ws, size_t ws_size,
                              hipStream_t stream) {
    const float* inputs = (const float*)d_in[0];
    const int* targets = (const int*)d_in[1];
    float* out = (float*)d_out;
    float* partial = (float*)d_ws;                                   // NVALS*GRID floats = 160 KB
    unsigned int* flags =
        (unsigned int*)((char*)d_ws + (size_t)NVALS * GRID * sizeof(float));  // GRID uints = 16 KB

    // Workspace is poisoned between iterations: zero the flags.
    // 16 KB async memset = cheap graph memset node, no extra kernel dispatch.
    hipMemsetAsync(flags, 0, GRID * sizeof(unsigned int), stream);
    mfe_fused<<<GRID, BLOCK, 0, stream>>>(inputs, targets, partial, flags, out);
}

// Round 5
// 138.267 us; speedup vs baseline: 1.0864x; 1.0276x over previous
//
#include <hip/hip_runtime.h>

#define NCLS 5
#define NSAMP 4194304
#define BLOCK 256
#define GRID 2048
#define SAMP_PER_BLOCK (NSAMP / GRID)             // 2048 samples/block, 8/thread
#define CHUNK_SAMP 1024                           // two chunks through one buffer
#define CHUNK_F4 (CHUNK_SAMP * NCLS / 4)          // 1280 float4 = 20480 B LDS
#define NVALS (2 * NCLS)                          // 5 sums + 5 counts

// CE without max-subtraction: logits are N(0,1) (|l| < ~6), exp cannot
// overflow/underflow harmfully; absmax threshold is 0.1975, error here ~1e-5.
__device__ __forceinline__ void accum_sample(float l0, float l1, float l2, float l3, float l4,
                                             int t, float sums[NCLS], unsigned int& packed_cnt) {
    float s = __expf(l0) + __expf(l1) + __expf(l2) + __expf(l3) + __expf(l4);
    float lt = (t == 0) ? l0 : (t == 1) ? l1 : (t == 2) ? l2 : (t == 3) ? l3 : l4;
    float ce = __logf(s) - lt;
#pragma unroll
    for (int k = 0; k < NCLS; ++k) {
        sums[k] += (t == k) ? ce : 0.0f;
    }
    packed_cnt += 1u << (6 * t);   // <=8 samples/thread, 6 bits/class: no overflow
}

// Block-level reduction of 10 values; threads 0..9 get the block total.
// `scratch` aliases the chunk LDS buffer: the leading __syncthreads makes the
// overwrite safe (all waves' chunk reads are register-complete before it).
__device__ __forceinline__ void block_reduce_10(float sums[NCLS], float cnts[NCLS],
                                                float* scratch, float* result10) {
#pragma unroll
    for (int k = 0; k < NCLS; ++k) {
#pragma unroll
        for (int off = 32; off > 0; off >>= 1) {
            sums[k] += __shfl_down(sums[k], off, 64);
            cnts[k] += __shfl_down(cnts[k], off, 64);
        }
    }
    const int lane = threadIdx.x & 63;
    const int wave = threadIdx.x >> 6;
    __syncthreads();                 // chunk-data reads done before aliasing scratch
    if (lane == 0) {
#pragma unroll
        for (int k = 0; k < NCLS; ++k) {
            scratch[wave * NVALS + k] = sums[k];
            scratch[wave * NVALS + NCLS + k] = cnts[k];
        }
    }
    __syncthreads();
    if (threadIdx.x < NVALS) {
        float v = 0.f;
#pragma unroll
        for (int w = 0; w < BLOCK / 64; ++w) v += scratch[w * NVALS + threadIdx.x];
        *result10 = v;
    }
}

// XOR swizzle on float4 slot index (involution, permutes within 8-slot/128B
// groups). Breaks the 8-way bank conflict of stride-5-f4 reads (lanes 8 apart
// alias: 20*8=160 words == 0 mod 32 banks) while keeping a wave's global
// access inside the same contiguous 1KB -> coalescing intact.
__device__ __forceinline__ int swz(int F) { return F ^ ((F >> 3) & 7); }

// global->LDS DMA, 16B/lane. Dest = wave-uniform base + lane*16 (HW rule);
// source address is per-lane. No VGPR staging -> no spill (round-3 lesson:
// register-staged chunks spilled 41MB to scratch).
__device__ __forceinline__ void gload_lds16(const float4* g, float4* l) {
    __builtin_amdgcn_global_load_lds(
        (__attribute__((address_space(1))) const void*)g,
        (__attribute__((address_space(3))) void*)l, 16, 0, 0);
}

// Fused single kernel.
// Handshake (round-1 lesson): no __threadfence (agent fence = buffer_wbl2+inv
// per block, ~110us), no contended atomic RMW (~100us). Relaxed agent-scope
// (sc1) stores/loads to the coherent point; one wave-level s_waitcnt vmcnt(0)
// orders partials->flag; fixed reducer block 0 polls per-block flags.
// Streaming (rounds 2-4 lessons): strided 80B-lane loads are L1-transaction-
// bound; register staging spills; global_load_lds staging works. Residency
// (round-4 lesson): GRID must fit ONE dispatch round -> GRID=2048 with LDS
// exactly 20480B (scratch aliased into chunk buffer) = 8 blocks/CU = 2048.
__global__ __launch_bounds__(BLOCK, 8) void mfe_fused(const float* __restrict__ inputs,
                                                      const int* __restrict__ targets,
                                                      float* __restrict__ partial /* [NVALS][GRID] */,
                                                      unsigned int* __restrict__ flags /* [GRID] */,
                                                      float* __restrict__ out) {
    const int T = threadIdx.x;
    const int b = blockIdx.x;
    const int w = T >> 6;                       // wave id 0..3
    const int lane = T & 63;
    const size_t samp0 = (size_t)b * SAMP_PER_BLOCK;
    const float4* gin0 = (const float4*)(inputs + samp0 * NCLS);
    const float4* gin1 = (const float4*)(inputs + (samp0 + CHUNK_SAMP) * NCLS);

    __shared__ float4 lds[CHUNK_F4];            // 20480 B exactly -> 8 blocks/CU

    // Targets: coalesced int4 (32 B/thread live total — no pressure).
    int4 tg0 = *(const int4*)(targets + samp0 + 4 * T);
    int4 tg1 = *(const int4*)(targets + samp0 + CHUNK_SAMP + 4 * T);

    float sums[NCLS] = {0.f, 0.f, 0.f, 0.f, 0.f};
    unsigned int packed = 0;
    float4 r[5];

    // ---- Chunk 0: DMA-stage (each wave 5 x 1KB), compute ----
#pragma unroll
    for (int j = 0; j < 5; ++j) {
        const int base = 320 * w + 64 * j;      // wave-uniform LDS base
        gload_lds16(gin0 + swz(base + lane), &lds[base]);
    }
    asm volatile("s_waitcnt vmcnt(0)" ::: "memory");   // this wave's DMAs (+tg) done
    __syncthreads();                                    // all waves' DMAs visible
#pragma unroll
    for (int k = 0; k < 5; ++k) r[k] = lds[swz(5 * T + k)];
    accum_sample(r[0].x, r[0].y, r[0].z, r[0].w, r[1].x, tg0.x, sums, packed);
    accum_sample(r[1].y, r[1].z, r[1].w, r[2].x, r[2].y, tg0.y, sums, packed);
    accum_sample(r[2].z, r[2].w, r[3].x, r[3].y, r[3].z, tg0.z, sums, packed);
    accum_sample(r[3].w, r[4].x, r[4].y, r[4].z, r[4].w, tg0.w, sums, packed);
    __syncthreads();                 // all chunk-0 reads done before restage

    // ---- Chunk 1 ----
#pragma unroll
    for (int j = 0; j < 5; ++j) {
        const int base = 320 * w + 64 * j;
        gload_lds16(gin1 + swz(base + lane), &lds[base]);
    }
    asm volatile("s_waitcnt vmcnt(0)" ::: "memory");
    __syncthreads();
#pragma unroll
    for (int k = 0; k < 5; ++k) r[k] = lds[swz(5 * T + k)];
    accum_sample(r[0].x, r[0].y, r[0].z, r[0].w, r[1].x, tg1.x, sums, packed);
    accum_sample(r[1].y, r[1].z, r[1].w, r[2].x, r[2].y, tg1.y, sums, packed);
    accum_sample(r[2].z, r[2].w, r[3].x, r[3].y, r[3].z, tg1.z, sums, packed);
    accum_sample(r[3].w, r[4].x, r[4].y, r[4].z, r[4].w, tg1.w, sums, packed);

    float cnts[NCLS];
#pragma unroll
    for (int k = 0; k < NCLS; ++k) {
        cnts[k] = (float)((packed >> (6 * k)) & 63u);
    }

    float* scratch = (float*)lds;    // alias: safe via barrier inside block_reduce_10
    float total;
    block_reduce_10(sums, cnts, scratch, &total);

    // ---- Publish partials (sc1 relaxed stores, straight to coherent point) ----
    if (threadIdx.x < NVALS) {
        __hip_atomic_store(&partial[threadIdx.x * GRID + blockIdx.x], total,
                           __ATOMIC_RELAXED, __HIP_MEMORY_SCOPE_AGENT);
    }
    // Wait until the sc1 stores above reached the coherent point, then set this
    // block's flag. asm "memory" clobber = compiler fence.
    asm volatile("s_waitcnt vmcnt(0)" ::: "memory");
    if (threadIdx.x == 0) {
        __hip_atomic_store(&flags[blockIdx.x], 1u,
                           __ATOMIC_RELAXED, __HIP_MEMORY_SCOPE_AGENT);
    }

    if (blockIdx.x != 0) return;

    // ---- Block 0: poll all flags (relaxed sc1 loads; control dep orders HW) ----
#pragma unroll 1
    for (int i = threadIdx.x; i < GRID; i += BLOCK) {
        while (__hip_atomic_load(&flags[i], __ATOMIC_RELAXED,
                                 __HIP_MEMORY_SCOPE_AGENT) == 0u) {
            __builtin_amdgcn_s_sleep(2);
        }
    }
    __syncthreads();                       // all flags observed by whole block
    asm volatile("" ::: "memory");         // don't hoist partial loads above polls

    // ---- Final reduce: sc1 loads of the 80KB partial array ----
    float fsums[NCLS], fcnts[NCLS];
#pragma unroll
    for (int k = 0; k < NCLS; ++k) {
        float s = 0.f, c = 0.f;
#pragma unroll
        for (int i = 0; i < GRID / BLOCK; ++i) {
            s += __hip_atomic_load(&partial[k * GRID + threadIdx.x + i * BLOCK],
                                   __ATOMIC_RELAXED, __HIP_MEMORY_SCOPE_AGENT);
            c += __hip_atomic_load(&partial[(NCLS + k) * GRID + threadIdx.x + i * BLOCK],
                                   __ATOMIC_RELAXED, __HIP_MEMORY_SCOPE_AGENT);
        }
        fsums[k] = s;
        fcnts[k] = c;
    }

    float ftot;
    block_reduce_10(fsums, fcnts, scratch, &ftot);

    __shared__ float fin[NVALS];
    if (threadIdx.x < NVALS) fin[threadIdx.x] = ftot;
    __syncthreads();
    if (threadIdx.x == 0) {
        float loss = 0.f;
#pragma unroll
        for (int k = 0; k < NCLS; ++k) {
            float cnt = fin[NCLS + k];
            if (cnt > 0.f) loss += fin[k] / cnt;
        }
        out[0] = loss;
    }
}

extern "C" void kernel_launch(void* const* d_in, const int* in_sizes, int n_in,
                              void* d_out, int out_size, void* d_ws, size_t ws_size,
                              hipStream_t stream) {
    const float* inputs = (const float*)d_in[0];
    const int* targets = (const int*)d_in[1];
    float* out = (float*)d_out;
    float* partial = (float*)d_ws;                                   // NVALS*GRID floats = 80 KB
    unsigned int* flags =
        (unsigned int*)((char*)d_ws + (size_t)NVALS * GRID * sizeof(float));  // GRID uints = 8 KB

    // Workspace is poisoned between iterations: zero the flags.
    // 8 KB async memset = cheap graph memset node, no extra kernel dispatch.
    hipMemsetAsync(flags, 0, GRID * sizeof(unsigned int), stream);
    mfe_fused<<<GRID, BLOCK, 0, stream>>>(inputs, targets, partial, flags, out);
}